// Round 4
// baseline (1095.321 us; speedup 1.0000x reference)
//
#include <hip/hip_runtime.h>
#include <hip/hip_bf16.h>
#include <math.h>

// Problem constants (from reference): B=2, N=4096, E=16384, D=64, OUT=64
#define BB 2
#define NN 4096      // 2^12
#define EE 16384     // 2^14
#define DD 64
#define OO 64
// flat element index in [B,N,E]: fe = b*(N*E) + n*E + e ; N*E = 2^26, E = 2^14

// clang native vector type — required by __builtin_nontemporal_load
// (HIP's uint4 is a class template and is rejected by the builtin).
typedef unsigned int v4u __attribute__((ext_vector_type(4)));

// ---------------------------------------------------------------------------
// Kernel 1: recover ri_idx/ro_idx from the one-hot incidence matrices, and
// zero the mi/mo accumulators (grid == 1,048,576 threads == mi+mo float count,
// so each thread zeroes exactly one float; removes a separate memset dispatch).
// Each [b,:,e] column has exactly one nonzero (1.0f) at row n -> unique writer
// per (b,e), plain stores. Must scan all 1.073 GB: HBM floor of the problem.
// Unroll x4 per matrix: 8 x 16B nontemporal loads in flight per thread,
// exactly 8 grid-stride iterations.
// ---------------------------------------------------------------------------
__global__ __launch_bounds__(256) void extract_idx_kernel(
    const v4u* __restrict__ Ri, const v4u* __restrict__ Ro,
    int* __restrict__ ri_idx, int* __restrict__ ro_idx,
    float* __restrict__ mi_mo)   // 2*B*N*D = 1,048,576 floats, contiguous
{
    unsigned gid = blockIdx.x * blockDim.x + threadIdx.x;
    mi_mo[gid] = 0.0f;           // stream-ordered: visible to scatter_kernel

    const unsigned total16 = (unsigned)BB * NN * (EE / 16);  // 8,388,608 blocks of 16 elems
    unsigned stride = gridDim.x * blockDim.x;                // 1,048,576
    for (unsigned i = gid; i < total16; i += stride) {       // 8 iterations
        unsigned i4 = i * 4u;
        v4u a0 = __builtin_nontemporal_load(&Ri[i4 + 0]);
        v4u a1 = __builtin_nontemporal_load(&Ri[i4 + 1]);
        v4u a2 = __builtin_nontemporal_load(&Ri[i4 + 2]);
        v4u a3 = __builtin_nontemporal_load(&Ri[i4 + 3]);
        v4u c0 = __builtin_nontemporal_load(&Ro[i4 + 0]);
        v4u c1 = __builtin_nontemporal_load(&Ro[i4 + 1]);
        v4u c2 = __builtin_nontemporal_load(&Ro[i4 + 2]);
        v4u c3 = __builtin_nontemporal_load(&Ro[i4 + 3]);
        unsigned fe = i * 16u;                 // flat element index in [B,N,E]
        int e = (int)(fe & (EE - 1));          // 16 consecutive e's, same (b,n)
        int n = (int)((fe >> 14) & (NN - 1));
        int b = (int)(fe >> 26);
        int base = b * EE + e;
        if (a0.x) ri_idx[base +  0] = n;
        if (a0.y) ri_idx[base +  1] = n;
        if (a0.z) ri_idx[base +  2] = n;
        if (a0.w) ri_idx[base +  3] = n;
        if (a1.x) ri_idx[base +  4] = n;
        if (a1.y) ri_idx[base +  5] = n;
        if (a1.z) ri_idx[base +  6] = n;
        if (a1.w) ri_idx[base +  7] = n;
        if (a2.x) ri_idx[base +  8] = n;
        if (a2.y) ri_idx[base +  9] = n;
        if (a2.z) ri_idx[base + 10] = n;
        if (a2.w) ri_idx[base + 11] = n;
        if (a3.x) ri_idx[base + 12] = n;
        if (a3.y) ri_idx[base + 13] = n;
        if (a3.z) ri_idx[base + 14] = n;
        if (a3.w) ri_idx[base + 15] = n;
        if (c0.x) ro_idx[base +  0] = n;
        if (c0.y) ro_idx[base +  1] = n;
        if (c0.z) ro_idx[base +  2] = n;
        if (c0.w) ro_idx[base +  3] = n;
        if (c1.x) ro_idx[base +  4] = n;
        if (c1.y) ro_idx[base +  5] = n;
        if (c1.z) ro_idx[base +  6] = n;
        if (c1.w) ro_idx[base +  7] = n;
        if (c2.x) ro_idx[base +  8] = n;
        if (c2.y) ro_idx[base +  9] = n;
        if (c2.z) ro_idx[base + 10] = n;
        if (c2.w) ro_idx[base + 11] = n;
        if (c3.x) ro_idx[base + 12] = n;
        if (c3.y) ro_idx[base + 13] = n;
        if (c3.z) ro_idx[base + 14] = n;
        if (c3.w) ro_idx[base + 15] = n;
    }
}

// ---------------------------------------------------------------------------
// Kernel 2: edge-weighted scatter-add.
// mi[b,ri,:] += w * X[b,ro,:];  mo[b,ro,:] += w * X[b,ri,:]
// 64 lanes per edge (one per feature). Coalesced gathers and atomic targets.
// ---------------------------------------------------------------------------
__global__ __launch_bounds__(256) void scatter_kernel(
    const float* __restrict__ X, const float* __restrict__ ew,
    const int* __restrict__ ri_idx, const int* __restrict__ ro_idx,
    float* __restrict__ mi, float* __restrict__ mo)
{
    int t = blockIdx.x * blockDim.x + threadIdx.x;
    int edge = t >> 6;                 // global edge id in [0, B*E)
    int lane = t & 63;
    if (edge >= BB * EE) return;
    int b = edge >> 14;                // E = 2^14
    float w = ew[edge];
    int ri = ri_idx[edge];
    int ro = ro_idx[edge];
    const float* xb = X + (size_t)b * NN * DD;
    float xro = xb[ro * DD + lane];
    float xri = xb[ri * DD + lane];
    float* mib = mi + (size_t)b * NN * DD;
    float* mob = mo + (size_t)b * NN * DD;
    atomicAdd(&mib[ri * DD + lane], w * xro);
    atomicAdd(&mob[ro * DD + lane], w * xri);
}

// ---------------------------------------------------------------------------
// Kernel 3: per-node MLP, one WAVE per node, lane j = output channel.
// acc_j = b1[j] + sum_k feat[k]*W1[k][j]; h=tanh; out_j = tanh(b2[j]+sum h W2).
// Features broadcast via __shfl; W rows are coalesced 256B loads (64KB working
// set, L1/L2-hot). 8192 waves -> full occupancy, ~1 VGPR accumulator.
// ---------------------------------------------------------------------------
__global__ __launch_bounds__(256) void mlp_kernel(
    const float* __restrict__ X, const float* __restrict__ mi,
    const float* __restrict__ mo,
    const float* __restrict__ W1, const float* __restrict__ b1,
    const float* __restrict__ W2, const float* __restrict__ b2,
    float* __restrict__ out)
{
    int wid = (blockIdx.x * blockDim.x + threadIdx.x) >> 6;   // node id
    int lane = threadIdx.x & 63;
    if (wid >= BB * NN) return;

    float acc = b1[lane];
    const float* srcs[3];
    srcs[0] = mi + (size_t)wid * DD;
    srcs[1] = mo + (size_t)wid * DD;
    srcs[2] = X  + (size_t)wid * DD;

    for (int part = 0; part < 3; ++part) {
        float fv = srcs[part][lane];          // lane k holds feat[k]
        const float* wbase = W1 + (size_t)part * DD * OO;
        #pragma unroll
        for (int k = 0; k < DD; ++k) {
            float fk = __shfl(fv, k, 64);
            acc += fk * wbase[k * OO + lane]; // coalesced row, L1-hot
        }
    }
    float h = tanhf(acc);

    float acc2 = b2[lane];
    #pragma unroll
    for (int k = 0; k < OO; ++k) {
        float hk = __shfl(h, k, 64);
        acc2 += hk * W2[k * OO + lane];
    }
    out[(size_t)wid * OO + lane] = tanhf(acc2);
}

// ---------------------------------------------------------------------------
extern "C" void kernel_launch(void* const* d_in, const int* in_sizes, int n_in,
                              void* d_out, int out_size, void* d_ws, size_t ws_size,
                              hipStream_t stream)
{
    const float* X  = (const float*)d_in[0];   // [B,N,D]
    const float* ew = (const float*)d_in[1];   // [B,E]
    const float* Ri = (const float*)d_in[2];   // [B,N,E]
    const float* Ro = (const float*)d_in[3];   // [B,N,E]
    const float* W1 = (const float*)d_in[4];   // [3D,OUT]
    const float* b1 = (const float*)d_in[5];   // [OUT]
    const float* W2 = (const float*)d_in[6];   // [OUT,OUT]
    const float* b2 = (const float*)d_in[7];   // [OUT]
    float* out = (float*)d_out;                // [B,N,OUT]

    // workspace layout (ws re-poisoned to 0xAA each call -> re-init all of it)
    float* mi = (float*)d_ws;                            // 2 MB
    float* mo = mi + (size_t)BB * NN * DD;               // 2 MB
    int* ri_idx = (int*)(mo + (size_t)BB * NN * DD);     // 128 KB
    int* ro_idx = ri_idx + BB * EE;                      // 128 KB

    // extract also zeroes mi/mo (grid size == mi+mo element count)
    extract_idx_kernel<<<4096, 256, 0, stream>>>(
        (const v4u*)Ri, (const v4u*)Ro, ri_idx, ro_idx, mi);

    scatter_kernel<<<(BB * EE * 64) / 256, 256, 0, stream>>>(
        X, ew, ri_idx, ro_idx, mi, mo);

    mlp_kernel<<<(BB * NN * 64) / 256, 256, 0, stream>>>(
        X, mi, mo, W1, b1, W2, b2, out);
}

// Round 5
// 1005.661 us; speedup vs baseline: 1.0892x; 1.0892x over previous
//
#include <hip/hip_runtime.h>
#include <hip/hip_bf16.h>
#include <math.h>

// Problem constants (from reference): B=2, N=4096, E=16384, D=64, OUT=64
#define BB 2
#define NN 4096      // 2^12
#define EE 16384     // 2^14
#define DD 64
#define OO 64
// flat element index in [B,N,E]: fe = b*(N*E) + n*E + e ; N*E = 2^26, E = 2^14

// clang native vector type — required by __builtin_nontemporal_load
// (HIP's uint4 is a class template and is rejected by the builtin).
typedef unsigned int v4u __attribute__((ext_vector_type(4)));

// ---------------------------------------------------------------------------
// Kernel 1: recover ri_idx/ro_idx from the one-hot incidence matrices, and
// zero the mi/mo accumulators (grid == 1,048,576 threads == mi+mo float count;
// removes a separate memset dispatch).
// R3-proven access pattern: 32 B per thread per matrix (unroll x2), 16
// grid-stride iterations. R4's x4 unroll (64 B/lane) regressed 9% — lane
// stride 64 B quadruples per-instruction L1 transactions vs unit stride;
// keep the x2 pattern.
// Each [b,:,e] column has exactly one nonzero (1.0f) at row n -> unique
// writer per (b,e), plain stores. Must scan all 1.073 GB: HBM floor.
// ---------------------------------------------------------------------------
__global__ __launch_bounds__(256) void extract_idx_kernel(
    const v4u* __restrict__ Ri, const v4u* __restrict__ Ro,
    int* __restrict__ ri_idx, int* __restrict__ ro_idx,
    float* __restrict__ mi_mo)   // 2*B*N*D = 1,048,576 floats, contiguous
{
    unsigned gid = blockIdx.x * blockDim.x + threadIdx.x;
    mi_mo[gid] = 0.0f;           // stream-ordered: visible to scatter_kernel

    const unsigned total8 = (unsigned)BB * NN * (EE / 8);   // 16,777,216 pairs of v4u
    unsigned stride = gridDim.x * blockDim.x;               // 1,048,576
    for (unsigned i = gid; i < total8; i += stride) {       // 16 iterations
        unsigned i4 = i * 2u;
        v4u a0 = __builtin_nontemporal_load(&Ri[i4]);
        v4u a1 = __builtin_nontemporal_load(&Ri[i4 + 1]);
        v4u c0 = __builtin_nontemporal_load(&Ro[i4]);
        v4u c1 = __builtin_nontemporal_load(&Ro[i4 + 1]);
        unsigned fe = i * 8u;                  // flat element index in [B,N,E]
        int e = (int)(fe & (EE - 1));          // 8 consecutive e's, same (b,n)
        int n = (int)((fe >> 14) & (NN - 1));
        int b = (int)(fe >> 26);
        int base = b * EE + e;
        if (a0.x) ri_idx[base + 0] = n;
        if (a0.y) ri_idx[base + 1] = n;
        if (a0.z) ri_idx[base + 2] = n;
        if (a0.w) ri_idx[base + 3] = n;
        if (a1.x) ri_idx[base + 4] = n;
        if (a1.y) ri_idx[base + 5] = n;
        if (a1.z) ri_idx[base + 6] = n;
        if (a1.w) ri_idx[base + 7] = n;
        if (c0.x) ro_idx[base + 0] = n;
        if (c0.y) ro_idx[base + 1] = n;
        if (c0.z) ro_idx[base + 2] = n;
        if (c0.w) ro_idx[base + 3] = n;
        if (c1.x) ro_idx[base + 4] = n;
        if (c1.y) ro_idx[base + 5] = n;
        if (c1.z) ro_idx[base + 6] = n;
        if (c1.w) ro_idx[base + 7] = n;
    }
}

// ---------------------------------------------------------------------------
// Kernel 2: edge-weighted scatter-add.
// mi[b,ri,:] += w * X[b,ro,:];  mo[b,ro,:] += w * X[b,ri,:]
// 64 lanes per edge (one per feature). Coalesced gathers and atomic targets.
// ---------------------------------------------------------------------------
__global__ __launch_bounds__(256) void scatter_kernel(
    const float* __restrict__ X, const float* __restrict__ ew,
    const int* __restrict__ ri_idx, const int* __restrict__ ro_idx,
    float* __restrict__ mi, float* __restrict__ mo)
{
    int t = blockIdx.x * blockDim.x + threadIdx.x;
    int edge = t >> 6;                 // global edge id in [0, B*E)
    int lane = t & 63;
    if (edge >= BB * EE) return;
    int b = edge >> 14;                // E = 2^14
    float w = ew[edge];
    int ri = ri_idx[edge];
    int ro = ro_idx[edge];
    const float* xb = X + (size_t)b * NN * DD;
    float xro = xb[ro * DD + lane];
    float xri = xb[ri * DD + lane];
    float* mib = mi + (size_t)b * NN * DD;
    float* mob = mo + (size_t)b * NN * DD;
    atomicAdd(&mib[ri * DD + lane], w * xro);
    atomicAdd(&mob[ro * DD + lane], w * xri);
}

// ---------------------------------------------------------------------------
// Kernel 3: per-node MLP, one WAVE per node, lane j = output channel.
// acc_j = b1[j] + sum_k feat[k]*W1[k][j]; h=tanh; out_j = tanh(b2[j]+sum h W2).
// Features broadcast via __shfl; W rows are coalesced 256B loads (64KB working
// set, L1/L2-hot). 8192 waves -> full occupancy, ~1 VGPR accumulator.
// ---------------------------------------------------------------------------
__global__ __launch_bounds__(256) void mlp_kernel(
    const float* __restrict__ X, const float* __restrict__ mi,
    const float* __restrict__ mo,
    const float* __restrict__ W1, const float* __restrict__ b1,
    const float* __restrict__ W2, const float* __restrict__ b2,
    float* __restrict__ out)
{
    int wid = (blockIdx.x * blockDim.x + threadIdx.x) >> 6;   // node id
    int lane = threadIdx.x & 63;
    if (wid >= BB * NN) return;

    float acc = b1[lane];
    const float* srcs[3];
    srcs[0] = mi + (size_t)wid * DD;
    srcs[1] = mo + (size_t)wid * DD;
    srcs[2] = X  + (size_t)wid * DD;

    for (int part = 0; part < 3; ++part) {
        float fv = srcs[part][lane];          // lane k holds feat[k]
        const float* wbase = W1 + (size_t)part * DD * OO;
        #pragma unroll
        for (int k = 0; k < DD; ++k) {
            float fk = __shfl(fv, k, 64);
            acc += fk * wbase[k * OO + lane]; // coalesced row, L1-hot
        }
    }
    float h = tanhf(acc);

    float acc2 = b2[lane];
    #pragma unroll
    for (int k = 0; k < OO; ++k) {
        float hk = __shfl(h, k, 64);
        acc2 += hk * W2[k * OO + lane];
    }
    out[(size_t)wid * OO + lane] = tanhf(acc2);
}

// ---------------------------------------------------------------------------
extern "C" void kernel_launch(void* const* d_in, const int* in_sizes, int n_in,
                              void* d_out, int out_size, void* d_ws, size_t ws_size,
                              hipStream_t stream)
{
    const float* X  = (const float*)d_in[0];   // [B,N,D]
    const float* ew = (const float*)d_in[1];   // [B,E]
    const float* Ri = (const float*)d_in[2];   // [B,N,E]
    const float* Ro = (const float*)d_in[3];   // [B,N,E]
    const float* W1 = (const float*)d_in[4];   // [3D,OUT]
    const float* b1 = (const float*)d_in[5];   // [OUT]
    const float* W2 = (const float*)d_in[6];   // [OUT,OUT]
    const float* b2 = (const float*)d_in[7];   // [OUT]
    float* out = (float*)d_out;                // [B,N,OUT]

    // workspace layout (ws re-poisoned to 0xAA each call -> re-init all of it)
    float* mi = (float*)d_ws;                            // 2 MB
    float* mo = mi + (size_t)BB * NN * DD;               // 2 MB
    int* ri_idx = (int*)(mo + (size_t)BB * NN * DD);     // 128 KB
    int* ro_idx = ri_idx + BB * EE;                      // 128 KB

    // extract also zeroes mi/mo (grid size == mi+mo element count)
    extract_idx_kernel<<<4096, 256, 0, stream>>>(
        (const v4u*)Ri, (const v4u*)Ro, ri_idx, ro_idx, mi);

    scatter_kernel<<<(BB * EE * 64) / 256, 256, 0, stream>>>(
        X, ew, ri_idx, ro_idx, mi, mo);

    mlp_kernel<<<(BB * NN * 64) / 256, 256, 0, stream>>>(
        X, mi, mo, W1, b1, W2, b2, out);
}